// Round 4
// baseline (836.177 us; speedup 1.0000x reference)
//
#include <hip/hip_runtime.h>
#include <hip/hip_bf16.h>

#define T_DIM 512
#define B_DIM 16
#define D_DIM 1024
#define N_DIM 512

typedef short s16x8 __attribute__((ext_vector_type(8)));
typedef float f32x4 __attribute__((ext_vector_type(4)));
typedef float f32x2 __attribute__((ext_vector_type(2)));

__device__ __forceinline__ unsigned short f2bf(float f) {
    unsigned u = __float_as_uint(f);
    unsigned r = (u + 0x7fffu + ((u >> 16) & 1u)) >> 16;
    return (unsigned short)r;
}

// sum over the 32 lanes of this half-wave, result broadcast to all 32.
__device__ __forceinline__ float half32_sum(float x) {
    x += __int_as_float(__builtin_amdgcn_update_dpp(0, __float_as_int(x), 0xB1,  0xf, 0xf, true)); // quad_perm[1,0,3,2]
    x += __int_as_float(__builtin_amdgcn_update_dpp(0, __float_as_int(x), 0x4E,  0xf, 0xf, true)); // quad_perm[2,3,0,1]
    x += __int_as_float(__builtin_amdgcn_update_dpp(0, __float_as_int(x), 0x124, 0xf, 0xf, true)); // row_ror:4
    x += __int_as_float(__builtin_amdgcn_update_dpp(0, __float_as_int(x), 0x128, 0xf, 0xf, true)); // row_ror:8
    x += __int_as_float(__builtin_amdgcn_ds_swizzle(__float_as_int(x), 0x401F));                   // xor 16
    return x;
}

// tanh via sinh: t = s * rsqrt(1+s^2), s = x*(1 + y/6 + y^2/120 + y^3/5040),
// y = x^2. sinh is entire -> Taylor converges; tanh error = ds/(1+s^2)^1.5,
// worst ~5e-5 near |x|~3, saturation exact for large |x|. 1 trans/element.
__device__ __forceinline__ f32x2 tanh2(f32x2 x) {
    const f32x2 c1 = {0.16666667f, 0.16666667f};        // 1/6
    const f32x2 c2 = {8.3333333e-3f, 8.3333333e-3f};    // 1/120
    const f32x2 c3 = {1.9841270e-4f, 1.9841270e-4f};    // 1/5040
    f32x2 y = x * x;
    f32x2 p = c2 + y * c3;
    p = c1 + y * p;
    f32x2 s = x + (x * y) * p;      // x*(1+y*(c1+y*(c2+y*c3)))
    f32x2 d = s * s + 1.0f;
    f32x2 r = { __builtin_amdgcn_rsqf(d.x), __builtin_amdgcn_rsqf(d.y) };
    return s * r;
}

// ---------------- projection GEMM: C[m,n] = sum_d x[m,d] * W[n,d] ----------
__global__ __launch_bounds__(256) void proj_gemm(
    const float* __restrict__ x,
    const float* __restrict__ Wk,
    const float* __restrict__ Wv,
    const float* __restrict__ Wq,
    float* __restrict__ kbuf, float* __restrict__ vbuf, float* __restrict__ qbuf)
{
    const float* W = (blockIdx.z == 0) ? Wk : (blockIdx.z == 1) ? Wv : Wq;
    float* out = (blockIdx.z == 0) ? kbuf : (blockIdx.z == 1) ? vbuf : qbuf;

    __shared__ __align__(16) unsigned short As[64 * 40];
    __shared__ __align__(16) unsigned short Bs[64 * 40];

    const int tid  = threadIdx.x;
    const int m0   = blockIdx.x * 64;
    const int n0   = blockIdx.y * 64;
    const int wave = tid >> 6;
    const int lane = tid & 63;
    const int l15  = lane & 15;
    const int quad = lane >> 4;

    const int srow = tid >> 2;
    const int scol = (tid & 3) * 8;

    f32x4 acc[4];
#pragma unroll
    for (int i = 0; i < 4; ++i) acc[i] = (f32x4)0.0f;

    for (int k0 = 0; k0 < D_DIM; k0 += 32) {
        __syncthreads();
        {
            const float* srcA = &x[(size_t)(m0 + srow) * D_DIM + k0 + scol];
            float4 a0 = *(const float4*)srcA;
            float4 a1 = *(const float4*)(srcA + 4);
            uint4 pa;
            pa.x = (unsigned)f2bf(a0.x) | ((unsigned)f2bf(a0.y) << 16);
            pa.y = (unsigned)f2bf(a0.z) | ((unsigned)f2bf(a0.w) << 16);
            pa.z = (unsigned)f2bf(a1.x) | ((unsigned)f2bf(a1.y) << 16);
            pa.w = (unsigned)f2bf(a1.z) | ((unsigned)f2bf(a1.w) << 16);
            *(uint4*)&As[srow * 40 + scol] = pa;

            const float* srcB = &W[(size_t)(n0 + srow) * D_DIM + k0 + scol];
            float4 b0 = *(const float4*)srcB;
            float4 b1 = *(const float4*)(srcB + 4);
            uint4 pb;
            pb.x = (unsigned)f2bf(b0.x) | ((unsigned)f2bf(b0.y) << 16);
            pb.y = (unsigned)f2bf(b0.z) | ((unsigned)f2bf(b0.w) << 16);
            pb.z = (unsigned)f2bf(b1.x) | ((unsigned)f2bf(b1.y) << 16);
            pb.w = (unsigned)f2bf(b1.z) | ((unsigned)f2bf(b1.w) << 16);
            *(uint4*)&Bs[srow * 40 + scol] = pb;
        }
        __syncthreads();
        s16x8 af = *(const s16x8*)&As[(wave * 16 + l15) * 40 + quad * 8];
#pragma unroll
        for (int nt = 0; nt < 4; ++nt) {
            s16x8 bf = *(const s16x8*)&Bs[(nt * 16 + l15) * 40 + quad * 8];
            acc[nt] = __builtin_amdgcn_mfma_f32_16x16x32_bf16(af, bf, acc[nt], 0, 0, 0);
        }
    }
#pragma unroll
    for (int nt = 0; nt < 4; ++nt) {
#pragma unroll
        for (int rg = 0; rg < 4; ++rg) {
            int row = m0 + wave * 16 + quad * 4 + rg;
            int col = n0 + nt * 16 + l15;
            out[(size_t)row * N_DIM + col] = acc[nt][rg];
        }
    }
}

// ---------------- k row-normalization (in place) ---------------------------
__global__ __launch_bounds__(256) void knorm(float* __restrict__ kbuf)
{
    const int wave = threadIdx.x >> 6;
    const int lane = threadIdx.x & 63;
    const int row  = blockIdx.x * 4 + wave;
    float* p = &kbuf[(size_t)row * N_DIM + lane * 8];
    float4 a = *(const float4*)p;
    float4 b = *(const float4*)(p + 4);
    float s = a.x*a.x + a.y*a.y + a.z*a.z + a.w*a.w
            + b.x*b.x + b.y*b.y + b.z*b.z + b.w*b.w;
#pragma unroll
    for (int m = 1; m < 64; m <<= 1) s += __shfl_xor(s, m, 64);
    float inv = 1.0f / (sqrtf(s) + 1e-6f);
    a.x *= inv; a.y *= inv; a.z *= inv; a.w *= inv;
    b.x *= inv; b.y *= inv; b.z *= inv; b.w *= inv;
    *(float4*)p = a;
    *(float4*)(p + 4) = b;
}

// ---------------- sequential scan ------------------------------------------
// grid(32, 16): x = 16-row chunk, y = batch. block 256.
// Lane (wave wv, half h, tj=lane&31) owns TWO rows {4*wv+2*h, +1} x 16 cols
// [16*tj..16*tj+15] of S (true scale). k/q staged in LDS double-buffered,
// stride-18-word padding (b64 reads <=2-way aliased = free). Reductions over
// the 32 tj lanes: 4x DPP adds (VALU) + 1 ds_swizzle xor16. One barrier/step.
__global__ __launch_bounds__(256) void scan_kernel(
    const float* __restrict__ kbuf, const float* __restrict__ vbuf,
    const float* __restrict__ qbuf, float* __restrict__ out)
{
    __shared__ __align__(16) float ks[2][576];
    __shared__ __align__(16) float qs[2][576];
    __shared__ float vs[2][16];

    const int tid  = threadIdx.x;
    const int lane = tid & 63;
    const int wv   = tid >> 6;
    const int h    = lane >> 5;
    const int tj   = lane & 31;
    const int b    = blockIdx.y;
    const int i0   = blockIdx.x * 16;
    const int r0   = 4 * wv + 2 * h;   // local rows r0, r0+1

    const int wA = 18 * (tid >> 3) + ((2 * tid) & 15); // staging write (words)
    const int rA = 18 * tj;                            // read base (words)

    f32x2 SA[8], SB[8];
#pragma unroll
    for (int u = 0; u < 8; ++u) { SA[u] = (f32x2)0.0f; SB[u] = (f32x2)0.0f; }

    float2 pk, pq; float pv = 0.0f;
    {   // prefetch t=0, stage into buf0, prefetch t=1 into regs
        const size_t o0 = (size_t)b * N_DIM;
        pk = *(const float2*)&kbuf[o0 + 2 * tid];
        pq = *(const float2*)&qbuf[o0 + 2 * tid];
        if (tid < 16) pv = vbuf[o0 + i0 + tid];
        *(float2*)&ks[0][wA] = pk;
        *(float2*)&qs[0][wA] = pq;
        if (tid < 16) vs[0][tid] = pv;
        const size_t o1 = (size_t)(B_DIM + b) * N_DIM;
        pk = *(const float2*)&kbuf[o1 + 2 * tid];
        pq = *(const float2*)&qbuf[o1 + 2 * tid];
        if (tid < 16) pv = vbuf[o1 + i0 + tid];
    }
    __syncthreads();

    for (int t = 0; t < T_DIM; ++t) {
        const int cb = t & 1, nb = cb ^ 1;
        const size_t ofs = ((size_t)t * B_DIM + b) * N_DIM;

        // stage t+1 (already in regs) into the other buffer
        if (t + 1 < T_DIM) {
            *(float2*)&ks[nb][wA] = pk;
            *(float2*)&qs[nb][wA] = pq;
            if (tid < 16) vs[nb][tid] = pv;
        }
        // issue global prefetch for t+2
        if (t + 2 < T_DIM) {
            const size_t o2 = ((size_t)(t + 2) * B_DIM + b) * N_DIM;
            pk = *(const float2*)&kbuf[o2 + 2 * tid];
            pq = *(const float2*)&qbuf[o2 + 2 * tid];
            if (tid < 16) pv = vbuf[o2 + i0 + tid];
        }

        f32x2 k2[8], q2[8];
#pragma unroll
        for (int u = 0; u < 8; ++u) {
            k2[u] = *(const f32x2*)&ks[cb][rA + 2 * u];
            q2[u] = *(const f32x2*)&qs[cb][rA + 2 * u];
        }
        const float v0 = vs[cb][r0];
        const float v1 = vs[cb][r0 + 1];

        // racc = sum_j S_ij k_j (2 partial accumulators per row)
        f32x2 pa0 = (f32x2)0.0f, pb0 = (f32x2)0.0f;
        f32x2 pa1 = (f32x2)0.0f, pb1 = (f32x2)0.0f;
#pragma unroll
        for (int u = 0; u < 8; u += 2) {
            pa0 += SA[u] * k2[u];  pb0 += SA[u + 1] * k2[u + 1];
            pa1 += SB[u] * k2[u];  pb1 += SB[u + 1] * k2[u + 1];
        }
        const float racc0 = half32_sum(pa0.x + pa0.y + pb0.x + pb0.y);
        const float racc1 = half32_sum(pa1.x + pa1.y + pb1.x + pb1.y);

        const float dp0 = v0 - racc0;
        const float dp1 = v1 - racc1;
        const f32x2 d0 = {dp0, dp0}, d1 = {dp1, dp1};

        // S_new = tanh(S + dp*k);  sq += S_new * q
        f32x2 sa0 = (f32x2)0.0f, sb0 = (f32x2)0.0f;
        f32x2 sa1 = (f32x2)0.0f, sb1 = (f32x2)0.0f;
#pragma unroll
        for (int u = 0; u < 8; ++u) {
            f32x2 snA = tanh2(SA[u] + d0 * k2[u]);
            f32x2 snB = tanh2(SB[u] + d1 * k2[u]);
            SA[u] = snA; SB[u] = snB;
            if (u & 1) { sb0 += snA * q2[u]; sb1 += snB * q2[u]; }
            else       { sa0 += snA * q2[u]; sa1 += snB * q2[u]; }
        }
        const float sq0 = half32_sum(sa0.x + sa0.y + sb0.x + sb0.y);
        const float sq1 = half32_sum(sa1.x + sa1.y + sb1.x + sb1.y);

        if (tj == 0) {
            float g0 = __builtin_amdgcn_rcpf(1.0f + __builtin_amdgcn_exp2f(-sq0 * 1.44269504f));
            float g1 = __builtin_amdgcn_rcpf(1.0f + __builtin_amdgcn_exp2f(-sq1 * 1.44269504f));
            out[ofs + i0 + r0]     = sq0 * sq0 * g0;
            out[ofs + i0 + r0 + 1] = sq1 * sq1 * g1;
        }
        __syncthreads();
    }

    // S_final -> d_out[T*B*N + ((b*N + i)*N + col)]
    const size_t base = (size_t)T_DIM * B_DIM * N_DIM;
    const size_t so0 = base + ((size_t)b * N_DIM + i0 + r0) * N_DIM + 16 * tj;
    const size_t so1 = so0 + N_DIM;
#pragma unroll
    for (int u = 0; u < 4; ++u) {
        float4 w0, w1;
        w0.x = SA[2*u].x;   w0.y = SA[2*u].y;
        w0.z = SA[2*u+1].x; w0.w = SA[2*u+1].y;
        w1.x = SB[2*u].x;   w1.y = SB[2*u].y;
        w1.z = SB[2*u+1].x; w1.w = SB[2*u+1].y;
        *(float4*)&out[so0 + 4 * u] = w0;
        *(float4*)&out[so1 + 4 * u] = w1;
    }
}

extern "C" void kernel_launch(void* const* d_in, const int* in_sizes, int n_in,
                              void* d_out, int out_size, void* d_ws, size_t ws_size,
                              hipStream_t stream) {
    const float* x  = (const float*)d_in[0];
    const float* Wk = (const float*)d_in[1];
    const float* Wv = (const float*)d_in[2];
    const float* Wq = (const float*)d_in[3];
    float* outp = (float*)d_out;

    const size_t MN = (size_t)T_DIM * B_DIM * N_DIM;
    float* kbuf = (float*)d_ws;
    float* vbuf = kbuf + MN;
    float* qbuf = vbuf + MN;

    proj_gemm<<<dim3(128, 8, 3), 256, 0, stream>>>(x, Wk, Wv, Wq, kbuf, vbuf, qbuf);
    knorm<<<2048, 256, 0, stream>>>(kbuf);
    scan_kernel<<<dim3(32, 16), 256, 0, stream>>>(kbuf, vbuf, qbuf, outp);
}

// Round 6
// 782.767 us; speedup vs baseline: 1.0682x; 1.0682x over previous
//
#include <hip/hip_runtime.h>
#include <hip/hip_bf16.h>

#define T_DIM 512
#define B_DIM 16
#define D_DIM 1024
#define N_DIM 512

// c-fold: store S' = C*S so the exp2 argument is a single fma.
// C = 2*log2(e); tanh via exp2: tanh(x) = 1 - 2/(exp2(C*x)+1)
#define C_FOLD  2.885390082f
#define INV_C   0.3465735903f

typedef short s16x8 __attribute__((ext_vector_type(8)));
typedef float f32x4 __attribute__((ext_vector_type(4)));
typedef float f32x2 __attribute__((ext_vector_type(2)));

__device__ __forceinline__ unsigned short f2bf(float f) {
    unsigned u = __float_as_uint(f);
    unsigned r = (u + 0x7fffu + ((u >> 16) & 1u)) >> 16;
    return (unsigned short)r;
}

// sum over the 32 lanes of this half-wave, result broadcast to all 32.
// xor1/xor2 via quad_perm, xor4/xor8 via row_ror (VALU pipe), xor16 via one
// ds_swizzle. Proven in R3 (passed, 713us).
__device__ __forceinline__ float half32_sum(float x) {
    x += __int_as_float(__builtin_amdgcn_update_dpp(0, __float_as_int(x), 0xB1,  0xf, 0xf, true)); // quad_perm[1,0,3,2]
    x += __int_as_float(__builtin_amdgcn_update_dpp(0, __float_as_int(x), 0x4E,  0xf, 0xf, true)); // quad_perm[2,3,0,1]
    x += __int_as_float(__builtin_amdgcn_update_dpp(0, __float_as_int(x), 0x124, 0xf, 0xf, true)); // row_ror:4
    x += __int_as_float(__builtin_amdgcn_update_dpp(0, __float_as_int(x), 0x128, 0xf, 0xf, true)); // row_ror:8
    x += __int_as_float(__builtin_amdgcn_ds_swizzle(__float_as_int(x), 0x401F));                   // xor 16
    return x;
}

// ---------------- projection GEMM: C[m,n] = sum_d x[m,d] * W[n,d] ----------
__global__ __launch_bounds__(256) void proj_gemm(
    const float* __restrict__ x,
    const float* __restrict__ Wk,
    const float* __restrict__ Wv,
    const float* __restrict__ Wq,
    float* __restrict__ kbuf, float* __restrict__ vbuf, float* __restrict__ qbuf)
{
    const float* W = (blockIdx.z == 0) ? Wk : (blockIdx.z == 1) ? Wv : Wq;
    float* out = (blockIdx.z == 0) ? kbuf : (blockIdx.z == 1) ? vbuf : qbuf;

    __shared__ __align__(16) unsigned short As[64 * 40];
    __shared__ __align__(16) unsigned short Bs[64 * 40];

    const int tid  = threadIdx.x;
    const int m0   = blockIdx.x * 64;
    const int n0   = blockIdx.y * 64;
    const int wave = tid >> 6;
    const int lane = tid & 63;
    const int l15  = lane & 15;
    const int quad = lane >> 4;

    const int srow = tid >> 2;
    const int scol = (tid & 3) * 8;

    f32x4 acc[4];
#pragma unroll
    for (int i = 0; i < 4; ++i) acc[i] = (f32x4)0.0f;

    for (int k0 = 0; k0 < D_DIM; k0 += 32) {
        __syncthreads();
        {
            const float* srcA = &x[(size_t)(m0 + srow) * D_DIM + k0 + scol];
            float4 a0 = *(const float4*)srcA;
            float4 a1 = *(const float4*)(srcA + 4);
            uint4 pa;
            pa.x = (unsigned)f2bf(a0.x) | ((unsigned)f2bf(a0.y) << 16);
            pa.y = (unsigned)f2bf(a0.z) | ((unsigned)f2bf(a0.w) << 16);
            pa.z = (unsigned)f2bf(a1.x) | ((unsigned)f2bf(a1.y) << 16);
            pa.w = (unsigned)f2bf(a1.z) | ((unsigned)f2bf(a1.w) << 16);
            *(uint4*)&As[srow * 40 + scol] = pa;

            const float* srcB = &W[(size_t)(n0 + srow) * D_DIM + k0 + scol];
            float4 b0 = *(const float4*)srcB;
            float4 b1 = *(const float4*)(srcB + 4);
            uint4 pb;
            pb.x = (unsigned)f2bf(b0.x) | ((unsigned)f2bf(b0.y) << 16);
            pb.y = (unsigned)f2bf(b0.z) | ((unsigned)f2bf(b0.w) << 16);
            pb.z = (unsigned)f2bf(b1.x) | ((unsigned)f2bf(b1.y) << 16);
            pb.w = (unsigned)f2bf(b1.z) | ((unsigned)f2bf(b1.w) << 16);
            *(uint4*)&Bs[srow * 40 + scol] = pb;
        }
        __syncthreads();
        s16x8 af = *(const s16x8*)&As[(wave * 16 + l15) * 40 + quad * 8];
#pragma unroll
        for (int nt = 0; nt < 4; ++nt) {
            s16x8 bf = *(const s16x8*)&Bs[(nt * 16 + l15) * 40 + quad * 8];
            acc[nt] = __builtin_amdgcn_mfma_f32_16x16x32_bf16(af, bf, acc[nt], 0, 0, 0);
        }
    }
#pragma unroll
    for (int nt = 0; nt < 4; ++nt) {
#pragma unroll
        for (int rg = 0; rg < 4; ++rg) {
            int row = m0 + wave * 16 + quad * 4 + rg;
            int col = n0 + nt * 16 + l15;
            out[(size_t)row * N_DIM + col] = acc[nt][rg];
        }
    }
}

// ---------------- k row-normalization (in place) ---------------------------
__global__ __launch_bounds__(256) void knorm(float* __restrict__ kbuf)
{
    const int wave = threadIdx.x >> 6;
    const int lane = threadIdx.x & 63;
    const int row  = blockIdx.x * 4 + wave;
    float* p = &kbuf[(size_t)row * N_DIM + lane * 8];
    float4 a = *(const float4*)p;
    float4 b = *(const float4*)(p + 4);
    float s = a.x*a.x + a.y*a.y + a.z*a.z + a.w*a.w
            + b.x*b.x + b.y*b.y + b.z*b.z + b.w*b.w;
#pragma unroll
    for (int m = 1; m < 64; m <<= 1) s += __shfl_xor(s, m, 64);
    float inv = 1.0f / (sqrtf(s) + 1e-6f);
    a.x *= inv; a.y *= inv; a.z *= inv; a.w *= inv;
    b.x *= inv; b.y *= inv; b.z *= inv; b.w *= inv;
    *(float4*)p = a;
    *(float4*)(p + 4) = b;
}

// ---------------- sequential scan ------------------------------------------
// grid(32, 16): x = 16-row chunk, y = batch. block 256.
// Lane (wave wv, half h, tj=lane&31) owns TWO rows {4*wv+2*h, +1} x 16 cols
// [16*tj..16*tj+15] of S' (= C*S). k/q double-buffered in LDS as 16 chunks of
// 32 cols, stride 36 words -> lane reads 4x ds_read_b128 at 36*(tj>>1)+16*(tj&1);
// every 8-lane phase hits 32 distinct banks (R1-proven conflict-free).
// Reductions: 4 DPP adds + 1 ds_swizzle xor16 (R3-proven). One barrier/step.
__global__ __launch_bounds__(256) void scan_kernel(
    const float* __restrict__ kbuf, const float* __restrict__ vbuf,
    const float* __restrict__ qbuf, float* __restrict__ out)
{
    __shared__ __align__(16) float ks[2][576];
    __shared__ __align__(16) float qs[2][576];
    __shared__ float vs[2][16];

    const int tid  = threadIdx.x;
    const int lane = tid & 63;
    const int wv   = tid >> 6;
    const int h    = lane >> 5;
    const int tj   = lane & 31;
    const int b    = blockIdx.y;
    const int i0   = blockIdx.x * 16;
    const int r0   = 4 * wv + 2 * h;   // local rows r0, r0+1

    // staging: thread writes logical cols {2tid, 2tid+1}: chunk=(2tid)>>5,
    // off=(2tid)&31 -> b64 write, conflict-free phases.
    const int wA = 36 * (tid >> 4) + ((2 * tid) & 31);
    // read: lane tj covers cols [16tj..16tj+15] = chunk tj>>1, half tj&1
    const int rA = 36 * (tj >> 1) + 16 * (tj & 1);

    f32x2 SA[8], SB[8];
#pragma unroll
    for (int u = 0; u < 8; ++u) { SA[u] = (f32x2)0.0f; SB[u] = (f32x2)0.0f; }

    float2 pk, pq; float pv = 0.0f;
    {   // stage t=0 into buf0; prefetch t=1 into regs
        const size_t o0 = (size_t)b * N_DIM;
        pk = *(const float2*)&kbuf[o0 + 2 * tid];
        pq = *(const float2*)&qbuf[o0 + 2 * tid];
        if (tid < 16) pv = vbuf[o0 + i0 + tid];
        *(float2*)&ks[0][wA] = pk;
        *(float2*)&qs[0][wA] = pq;
        if (tid < 16) vs[0][tid] = pv;
        const size_t o1 = (size_t)(B_DIM + b) * N_DIM;
        pk = *(const float2*)&kbuf[o1 + 2 * tid];
        pq = *(const float2*)&qbuf[o1 + 2 * tid];
        if (tid < 16) pv = vbuf[o1 + i0 + tid];
    }
    __syncthreads();

    const f32x2 Cv   = {C_FOLD, C_FOLD};
    const f32x2 M2Cv = {-2.0f * C_FOLD, -2.0f * C_FOLD};

    for (int t = 0; t < T_DIM; ++t) {
        const int cb = t & 1, nb = cb ^ 1;
        const size_t ofs = ((size_t)t * B_DIM + b) * N_DIM;

        // stage t+1 (already in regs) into the other buffer
        if (t + 1 < T_DIM) {
            *(float2*)&ks[nb][wA] = pk;
            *(float2*)&qs[nb][wA] = pq;
            if (tid < 16) vs[nb][tid] = pv;
        }
        // issue global prefetch for t+2
        if (t + 2 < T_DIM) {
            const size_t o2 = ((size_t)(t + 2) * B_DIM + b) * N_DIM;
            pk = *(const float2*)&kbuf[o2 + 2 * tid];
            pq = *(const float2*)&qbuf[o2 + 2 * tid];
            if (tid < 16) pv = vbuf[o2 + i0 + tid];
        }

        f32x2 k2[8], q2[8];
#pragma unroll
        for (int u = 0; u < 4; ++u) {
            f32x4 kv = *(const f32x4*)&ks[cb][rA + 4 * u];
            f32x4 qv = *(const f32x4*)&qs[cb][rA + 4 * u];
            k2[2*u] = kv.xy; k2[2*u+1] = kv.zw;
            q2[2*u] = qv.xy; q2[2*u+1] = qv.zw;
        }
        const float v0 = vs[cb][r0];
        const float v1 = vs[cb][r0 + 1];

        // racc' = sum_j S'_ij k_j (2 partial accumulators per row)
        f32x2 pa0 = (f32x2)0.0f, pb0 = (f32x2)0.0f;
        f32x2 pa1 = (f32x2)0.0f, pb1 = (f32x2)0.0f;
#pragma unroll
        for (int u = 0; u < 8; u += 2) {
            pa0 += SA[u] * k2[u];  pb0 += SA[u + 1] * k2[u + 1];
            pa1 += SB[u] * k2[u];  pb1 += SB[u + 1] * k2[u + 1];
        }
        const float racc0 = half32_sum(pa0.x + pa0.y + pb0.x + pb0.y);
        const float racc1 = half32_sum(pa1.x + pa1.y + pb1.x + pb1.y);

        const float dp0 = __builtin_fmaf(C_FOLD, v0, -racc0);
        const float dp1 = __builtin_fmaf(C_FOLD, v1, -racc1);
        const f32x2 d0 = {dp0, dp0}, d1 = {dp1, dp1};

        // S'_new = C - 2C*rcp(exp2(S' + dp'*k)+1);  sq' += S'_new * q
        // 4 chains interleaved (SA/SB x u/u+1) for ILP.
        f32x2 sa0 = (f32x2)0.0f, sb0 = (f32x2)0.0f;
        f32x2 sa1 = (f32x2)0.0f, sb1 = (f32x2)0.0f;
#pragma unroll
        for (int u = 0; u < 8; u += 2) {
            f32x2 aA0 = SA[u]     + d0 * k2[u];
            f32x2 aB0 = SB[u]     + d1 * k2[u];
            f32x2 aA1 = SA[u + 1] + d0 * k2[u + 1];
            f32x2 aB1 = SB[u + 1] + d1 * k2[u + 1];
            f32x2 eA0 = { __builtin_amdgcn_exp2f(aA0.x), __builtin_amdgcn_exp2f(aA0.y) };
            f32x2 eB0 = { __builtin_amdgcn_exp2f(aB0.x), __builtin_amdgcn_exp2f(aB0.y) };
            f32x2 eA1 = { __builtin_amdgcn_exp2f(aA1.x), __builtin_amdgcn_exp2f(aA1.y) };
            f32x2 eB1 = { __builtin_amdgcn_exp2f(aB1.x), __builtin_amdgcn_exp2f(aB1.y) };
            eA0 = eA0 + 1.0f; eB0 = eB0 + 1.0f; eA1 = eA1 + 1.0f; eB1 = eB1 + 1.0f;
            f32x2 rA0 = { __builtin_amdgcn_rcpf(eA0.x), __builtin_amdgcn_rcpf(eA0.y) };
            f32x2 rB0 = { __builtin_amdgcn_rcpf(eB0.x), __builtin_amdgcn_rcpf(eB0.y) };
            f32x2 rA1 = { __builtin_amdgcn_rcpf(eA1.x), __builtin_amdgcn_rcpf(eA1.y) };
            f32x2 rB1 = { __builtin_amdgcn_rcpf(eB1.x), __builtin_amdgcn_rcpf(eB1.y) };
            f32x2 nA0 = Cv + rA0 * M2Cv;
            f32x2 nB0 = Cv + rB0 * M2Cv;
            f32x2 nA1 = Cv + rA1 * M2Cv;
            f32x2 nB1 = Cv + rB1 * M2Cv;
            SA[u] = nA0; SB[u] = nB0; SA[u + 1] = nA1; SB[u + 1] = nB1;
            sa0 += nA0 * q2[u];     sa1 += nB0 * q2[u];
            sb0 += nA1 * q2[u + 1]; sb1 += nB1 * q2[u + 1];
        }
        const float sq0 = half32_sum(sa0.x + sa0.y + sb0.x + sb0.y);
        const float sq1 = half32_sum(sa1.x + sa1.y + sb1.x + sb1.y);

        if (tj == 0) {
            float s0 = sq0 * INV_C, s1 = sq1 * INV_C;
            float g0 = __builtin_amdgcn_rcpf(1.0f + __builtin_amdgcn_exp2f(-s0 * 1.44269504f));
            float g1 = __builtin_amdgcn_rcpf(1.0f + __builtin_amdgcn_exp2f(-s1 * 1.44269504f));
            out[ofs + i0 + r0]     = s0 * s0 * g0;
            out[ofs + i0 + r0 + 1] = s1 * s1 * g1;
        }
        __syncthreads();
    }

    // S_final (true scale) -> d_out[T*B*N + ((b*N + i)*N + col)]
    const size_t base = (size_t)T_DIM * B_DIM * N_DIM;
    const size_t so0 = base + ((size_t)b * N_DIM + i0 + r0) * N_DIM + 16 * tj;
    const size_t so1 = so0 + N_DIM;
#pragma unroll
    for (int u = 0; u < 4; ++u) {
        float4 w0, w1;
        w0.x = SA[2*u].x   * INV_C; w0.y = SA[2*u].y   * INV_C;
        w0.z = SA[2*u+1].x * INV_C; w0.w = SA[2*u+1].y * INV_C;
        w1.x = SB[2*u].x   * INV_C; w1.y = SB[2*u].y   * INV_C;
        w1.z = SB[2*u+1].x * INV_C; w1.w = SB[2*u+1].y * INV_C;
        *(float4*)&out[so0 + 4 * u] = w0;
        *(float4*)&out[so1 + 4 * u] = w1;
    }
}

extern "C" void kernel_launch(void* const* d_in, const int* in_sizes, int n_in,
                              void* d_out, int out_size, void* d_ws, size_t ws_size,
                              hipStream_t stream) {
    const float* x  = (const float*)d_in[0];
    const float* Wk = (const float*)d_in[1];
    const float* Wv = (const float*)d_in[2];
    const float* Wq = (const float*)d_in[3];
    float* outp = (float*)d_out;

    const size_t MN = (size_t)T_DIM * B_DIM * N_DIM;
    float* kbuf = (float*)d_ws;
    float* vbuf = kbuf + MN;
    float* qbuf = vbuf + MN;

    proj_gemm<<<dim3(128, 8, 3), 256, 0, stream>>>(x, Wk, Wv, Wq, kbuf, vbuf, qbuf);
    knorm<<<2048, 256, 0, stream>>>(kbuf);
    scan_kernel<<<dim3(32, 16), 256, 0, stream>>>(kbuf, vbuf, qbuf, outp);
}